// Round 13
// baseline (341.493 us; speedup 1.0000x reference)
//
#include <hip/hip_runtime.h>
#include <hip/hip_bf16.h>
#include <stdint.h>

#define NN   32768
#define EE   524288
#define DD   128
#define D2   256
#define NPER 2048

using f32x4 = __attribute__((ext_vector_type(4))) float;
using sh8   = __attribute__((ext_vector_type(8))) short;
using sh4   = __attribute__((ext_vector_type(4))) short;

__device__ inline uint32_t rtn_hi_bits(float x){
  uint32_t u = __float_as_uint(x);
  return (u + 0x7FFFu + ((u >> 16) & 1u)) & 0xFFFF0000u;
}

// XCD-contiguous node mapping (8 XCDs, round-robin block dispatch)
__device__ inline int swz_node(int blk, int wave){
  int s = (blk & 7) * 1024 + (blk >> 3);
  return s * 4 + wave;
}

// ---------------- CSR build ----------------
__global__ __launch_bounds__(1024)
void k_scan(const int* __restrict__ cnt, int* __restrict__ rowptr){
  __shared__ int ps[1024];
  int t = threadIdx.x;
  int loc[32];
  int base = t * 32;
  int s = 0;
  #pragma unroll
  for (int j = 0; j < 32; ++j){ loc[j] = cnt[base + j]; s += loc[j]; }
  ps[t] = s; __syncthreads();
  for (int off = 1; off < 1024; off <<= 1){
    int v = (t >= off) ? ps[t - off] : 0;
    __syncthreads();
    ps[t] += v;
    __syncthreads();
  }
  int run = ps[t] - s;
  #pragma unroll
  for (int j = 0; j < 32; ++j){ rowptr[base + j] = run; run += loc[j]; }
  if (t == 1023) rowptr[NN] = run;
}

__global__ void k_scatter(const int* __restrict__ src, const int* __restrict__ dst,
                          const float* __restrict__ w, const int* __restrict__ rowptr,
                          int* __restrict__ cur, int* __restrict__ es, float* __restrict__ ew){
  int e = blockIdx.x * 256 + threadIdx.x;
  if (e < EE){
    int d = dst[e];
    int pos = rowptr[d] + atomicAdd(&cur[d], 1);
    es[pos] = src[e];
    ew[pos] = w[e];
  }
}

// ---------------- fused: degree count (blocks 0..2047) + weight prepack (2048..2175) ----------------
// A-frag (16x16x32): lane l holds A[m = l&15][k = (l>>4)*4 + (j&3) + 16*(j>>2)], j=0..7
__global__ __launch_bounds__(256)
void k_count_pack(const int* __restrict__ dst, int* __restrict__ cnt,
                  const float* __restrict__ W1, const float* __restrict__ W2,
                  ushort* __restrict__ W1h, ushort* __restrict__ W1l,
                  ushort* __restrict__ W2h, ushort* __restrict__ W2l){
  int b = blockIdx.x;
  if (b < 2048){
    int e = b * 256 + threadIdx.x;
    atomicAdd(&cnt[dst[e]], 1);
  } else if (b < 2112){
    int t = (b - 2048) * 256 + threadIdx.x;   // t = (((layer*4+kt)*16+mt)*64+lane)
    int lane = t & 63, mt = (t >> 6) & 15, kt = (t >> 10) & 3, layer = t >> 12;
    int nl = lane & 15, g = lane >> 4;
    int ucol = mt * 16 + nl;
    const float* Wp = W1 + layer * (DD * D2);
    sh8 hh, ll;
    #pragma unroll
    for (int j = 0; j < 8; ++j){
      int k = kt * 32 + g * 4 + (j & 3) + 16 * (j >> 2);
      float v = Wp[k * D2 + ucol];             // W1^T[ucol][k]
      uint32_t hb = rtn_hi_bits(v);
      hh[j] = (short)(hb >> 16);
      ll[j] = (short)(__float_as_uint(v - __uint_as_float(hb)) >> 16);
    }
    *(sh8*)(W1h + t * 8) = hh;
    *(sh8*)(W1l + t * 8) = ll;
  } else {
    int t = (b - 2112) * 256 + threadIdx.x;   // t = (((layer*8+kt)*8+mt)*64+lane)
    int lane = t & 63, mt = (t >> 6) & 7, kt = (t >> 9) & 7, layer = t >> 12;
    int nl = lane & 15, g = lane >> 4;
    int xcol = mt * 16 + nl;
    const float* Wp = W2 + layer * (D2 * DD);
    sh8 hh, ll;
    #pragma unroll
    for (int j = 0; j < 8; ++j){
      int k = kt * 32 + g * 4 + (j & 3) + 16 * (j >> 2); // k = ucol
      float v = Wp[k * DD + xcol];             // W2^T[xcol][ucol]
      uint32_t hb = rtn_hi_bits(v);
      hh[j] = (short)(hb >> 16);
      ll[j] = (short)(__float_as_uint(v - __uint_as_float(hb)) >> 16);
    }
    *(sh8*)(W2h + t * 8) = hh;
    *(sh8*)(W2l + t * 8) = ll;
  }
}

// ---------------- edge aggregation -> H emitted as bf16 hi/lo planes ----------------
// 2-wave edge-split: each node's edge range [r0,r1) splits at mid; two waves run
// the round-6 inner loop on their half, partial (s,a) combined exactly via LDS.
// Halves the per-wave serial gather chain without duplicating the edge walk.
template<int MODE>
__global__ __launch_bounds__(256)
void k_edge(const float* __restrict__ Zf, const float* __restrict__ cvec,
            const float* __restrict__ nW, const float* __restrict__ nb,
            const int* __restrict__ rowptr,
            const int* __restrict__ es, const float* __restrict__ ew,
            const float* __restrict__ eW, const float* __restrict__ eB,
            const float* __restrict__ ts, int layer,
            ushort* __restrict__ Hh, ushort* __restrict__ Hl){
  __shared__ float4 comb[2][2][64];   // [node][half][lane] partial {s0,s1,a0,a1}
  int wv = threadIdx.x >> 6;          // 0..3
  int ni = wv >> 1;                   // node within block
  int hf = wv & 1;                    // edge-half
  int s2 = (blockIdx.x & 7) * 2048 + (blockIdx.x >> 3);   // XCD-contiguous pair
  int n  = s2 * 2 + ni;
  int ld = threadIdx.x & 63;
  int d0 = ld * 2;
  float t  = ts[layer];
  float wx = eW[d0], wy = eW[d0 + 1];
  float bx = eB[d0], by = eB[d0 + 1];
  float nwx = 0.f, nwy = 0.f, nbx = 0.f, nby = 0.f;
  if (MODE == 0){ nwx = nW[d0]; nwy = nW[d0 + 1]; nbx = nb[d0]; nby = nb[d0 + 1]; }
  int r0 = __builtin_amdgcn_readfirstlane(rowptr[n]);
  int r1 = __builtin_amdgcn_readfirstlane(rowptr[n + 1]);
  int mid = (r0 + r1 + 1) >> 1;
  int ja = hf ? mid : r0;
  int jb = hf ? r1  : mid;

  float s0a = 0.f, s1a = 0.f, a0a = 0.f, a1a = 0.f;

  auto body = [&](float zx, float zy, float wj){
    float m0 = fmaxf(zx + fmaf(wj, wx, bx), 0.f) + 1e-7f;
    float m1 = fmaxf(zy + fmaf(wj, wy, by), 0.f) + 1e-7f;
    float p0 = __expf(fminf(m0 * t, 60.f));
    float p1 = __expf(fminf(m1 * t, 60.f));
    s0a += p0; a0a = fmaf(p0, m0, a0a);
    s1a += p1; a1a = fmaf(p1, m1, a1a);
  };

  int j = ja;
  for (; j + 4 <= jb; j += 4){
    int   sA = es[j],     sB = es[j + 1], sC = es[j + 2], sD = es[j + 3];
    float wA = ew[j],     wB = ew[j + 1], wC = ew[j + 2], wD = ew[j + 3];
    float zAx, zAy, zBx, zBy, zCx, zCy, zDx, zDy;
    if (MODE == 0){
      float cA = cvec[sA], cB = cvec[sB], cC = cvec[sC], cD = cvec[sD];
      zAx = fmaf(cA, nwx, nbx); zAy = fmaf(cA, nwy, nby);
      zBx = fmaf(cB, nwx, nbx); zBy = fmaf(cB, nwy, nby);
      zCx = fmaf(cC, nwx, nbx); zCy = fmaf(cC, nwy, nby);
      zDx = fmaf(cD, nwx, nbx); zDy = fmaf(cD, nwy, nby);
    } else {
      float2 zA = *(const float2*)(Zf + (size_t)sA * DD + d0);
      float2 zB = *(const float2*)(Zf + (size_t)sB * DD + d0);
      float2 zC = *(const float2*)(Zf + (size_t)sC * DD + d0);
      float2 zD = *(const float2*)(Zf + (size_t)sD * DD + d0);
      zAx = zA.x; zAy = zA.y; zBx = zB.x; zBy = zB.y;
      zCx = zC.x; zCy = zC.y; zDx = zD.x; zDy = zD.y;
    }
    body(zAx, zAy, wA); body(zBx, zBy, wB);
    body(zCx, zCy, wC); body(zDx, zDy, wD);
  }
  for (; j < jb; ++j){
    int s = es[j]; float w = ew[j];
    float zx, zy;
    if (MODE == 0){
      float cs = cvec[s];
      zx = fmaf(cs, nwx, nbx); zy = fmaf(cs, nwy, nby);
    } else {
      float2 z = *(const float2*)(Zf + (size_t)s * DD + d0);
      zx = z.x; zy = z.y;
    }
    body(zx, zy, w);
  }

  comb[ni][hf][ld] = make_float4(s0a, s1a, a0a, a1a);
  __syncthreads();
  if (hf == 0){
    float4 o = comb[ni][1][ld];
    s0a += o.x; s1a += o.y; a0a += o.z; a1a += o.w;
    float znx, zny;
    if (MODE == 0){
      float cn = cvec[n];
      znx = fmaf(cn, nwx, nbx); zny = fmaf(cn, nwy, nby);
    } else {
      float2 zn2 = *(const float2*)(Zf + (size_t)n * DD + d0);
      znx = zn2.x; zny = zn2.y;
    }
    float hx = fmaf(a0a, __builtin_amdgcn_rcpf(s0a + 1e-16f), znx);
    float hy = fmaf(a1a, __builtin_amdgcn_rcpf(s1a + 1e-16f), zny);
    uint32_t hbx = rtn_hi_bits(hx), hby = rtn_hi_bits(hy);
    uint32_t hw = (hbx >> 16) | (hby & 0xFFFF0000u);
    float lx = hx - __uint_as_float(hbx), ly = hy - __uint_as_float(hby);
    uint32_t lw = (__float_as_uint(lx) >> 16) | (__float_as_uint(ly) & 0xFFFF0000u);
    ((uint32_t*)(Hh + (size_t)n * DD))[ld] = hw;
    ((uint32_t*)(Hl + (size_t)n * DD))[ld] = lw;
  }
}

// ---------------- fused MFMA MLP (+ next-layer pre-LN, or final projection) ----------------
__global__ __launch_bounds__(256, 2)
void k_mlp(const ushort* __restrict__ Hhi, const ushort* __restrict__ Hlo,
           const ushort* __restrict__ W1h, const ushort* __restrict__ W1l,
           const float* __restrict__ b1, const float* __restrict__ g1,
           const float* __restrict__ be1,
           const ushort* __restrict__ W2h, const ushort* __restrict__ W2l,
           const float* __restrict__ b2, const float* __restrict__ Xres,
           float* __restrict__ Xout,
           const float* __restrict__ lnG, const float* __restrict__ lnB,
           float* __restrict__ Zout,
           const float* __restrict__ linW, float* __restrict__ yv,
           int hasRes, int writeX, int doFin)
{
  __shared__ ushort Ufh[16384];     // 32KB: U' hi frags [8kt][4nt][64lane][8]
  __shared__ ushort Ufl[16384];     // 32KB: U' lo frags
  __shared__ float2 Pln[256];       // [64 node][4 wave] LN partials

  const int tid = threadIdx.x;
  const int w = tid >> 6, l = tid & 63, nl = l & 15, g = l >> 4;
  const int bs = (blockIdx.x & 7) * 64 + (blockIdx.x >> 3);
  const int n0 = bs * 64;

  f32x4 acc[4][4];                  // [mi(ucol tile)][nt(node tile)]
  #pragma unroll
  for (int mi = 0; mi < 4; ++mi)
    #pragma unroll
    for (int nt = 0; nt < 4; ++nt) acc[mi][nt] = (f32x4)0.f;

  const int hbase = (n0 + nl) * DD + g * 4;

  // ---- GEMM1: U^T = W1^T · H^T, K = 128 (4 ksteps) ----
  #pragma unroll
  for (int kt = 0; kt < 4; ++kt){
    sh8 ah[4], al[4];
    #pragma unroll
    for (int mi = 0; mi < 4; ++mi){
      int fi = ((kt * 16 + w * 4 + mi) * 64 + l) * 8;
      ah[mi] = *(const sh8*)(W1h + fi);
      al[mi] = *(const sh8*)(W1l + fi);
    }
    sh8 bh[4], bl[4];
    #pragma unroll
    for (int nt = 0; nt < 4; ++nt){
      int hi_ = hbase + nt * 16 * DD + kt * 32;
      sh8 vh, vl;
      ((sh4*)&vh)[0] = *(const sh4*)(Hhi + hi_);
      ((sh4*)&vh)[1] = *(const sh4*)(Hhi + hi_ + 16);
      ((sh4*)&vl)[0] = *(const sh4*)(Hlo + hi_);
      ((sh4*)&vl)[1] = *(const sh4*)(Hlo + hi_ + 16);
      bh[nt] = vh; bl[nt] = vl;
    }
    #pragma unroll
    for (int mi = 0; mi < 4; ++mi)
      #pragma unroll
      for (int nt = 0; nt < 4; ++nt){
        acc[mi][nt] = __builtin_amdgcn_mfma_f32_16x16x32_bf16(ah[mi], bh[nt], acc[mi][nt], 0, 0, 0);
        acc[mi][nt] = __builtin_amdgcn_mfma_f32_16x16x32_bf16(ah[mi], bl[nt], acc[mi][nt], 0, 0, 0);
        acc[mi][nt] = __builtin_amdgcn_mfma_f32_16x16x32_bf16(al[mi], bh[nt], acc[mi][nt], 0, 0, 0);
      }
  }

  // ---- + b1, LN(256) stats (partial per wave, combine via LDS) ----
  #pragma unroll
  for (int mi = 0; mi < 4; ++mi){
    f32x4 bv = *(const f32x4*)(b1 + w * 64 + mi * 16 + g * 4);
    #pragma unroll
    for (int nt = 0; nt < 4; ++nt) acc[mi][nt] += bv;
  }
  float s1[4], s2[4];
  #pragma unroll
  for (int nt = 0; nt < 4; ++nt){
    float a = 0.f, b = 0.f;
    #pragma unroll
    for (int mi = 0; mi < 4; ++mi)
      #pragma unroll
      for (int r = 0; r < 4; ++r){ float v = acc[mi][nt][r]; a += v; b += v * v; }
    a += __shfl_xor(a, 16); b += __shfl_xor(b, 16);
    a += __shfl_xor(a, 32); b += __shfl_xor(b, 32);
    s1[nt] = a; s2[nt] = b;
  }
  {
    float p1 = (g == 0) ? s1[0] : (g == 1) ? s1[1] : (g == 2) ? s1[2] : s1[3];
    float p2 = (g == 0) ? s2[0] : (g == 1) ? s2[1] : (g == 2) ? s2[2] : s2[3];
    Pln[(g * 16 + nl) * 4 + w] = make_float2(p1, p2);
  }
  __syncthreads();

  // ---- LN apply + ReLU + split to bf16 hi/lo frags in LDS ----
  {
    f32x4 gv[4], ev[4];
    #pragma unroll
    for (int mi = 0; mi < 4; ++mi){
      gv[mi] = *(const f32x4*)(g1  + w * 64 + mi * 16 + g * 4);
      ev[mi] = *(const f32x4*)(be1 + w * 64 + mi * 16 + g * 4);
    }
    #pragma unroll
    for (int nt = 0; nt < 4; ++nt){
      int node = nt * 16 + nl;
      float t1 = 0.f, t2 = 0.f;
      #pragma unroll
      for (int wi = 0; wi < 4; ++wi){
        float2 pp = Pln[node * 4 + wi];
        t1 += pp.x; t2 += pp.y;
      }
      float mean = t1 * (1.f / D2);
      float var  = t2 * (1.f / D2) - mean * mean;
      float rstd = 1.f / sqrtf(var + 1e-5f);
      #pragma unroll
      for (int p = 0; p < 2; ++p){
        sh8 uh, ul;
        #pragma unroll
        for (int j = 0; j < 8; ++j){
          int mi = 2 * p + (j >> 2), r = j & 3;
          float v = (acc[mi][nt][r] - mean) * rstd * gv[mi][r] + ev[mi][r];
          v = fmaxf(v, 0.f);
          uint32_t hb = rtn_hi_bits(v);
          uh[j] = (short)(hb >> 16);
          ul[j] = (short)(__float_as_uint(v - __uint_as_float(hb)) >> 16);
        }
        int fo = (((2 * w + p) * 4 + nt) * 64 + l) * 8;
        *(sh8*)(Ufh + fo) = uh;
        *(sh8*)(Ufl + fo) = ul;
      }
    }
  }
  __syncthreads();

  // ---- GEMM2: X2^T = W2^T · U'^T, K = 256 (8 ksteps) ----
  f32x4 a2[2][4];
  #pragma unroll
  for (int mi = 0; mi < 2; ++mi)
    #pragma unroll
    for (int nt = 0; nt < 4; ++nt) a2[mi][nt] = (f32x4)0.f;
  #pragma unroll
  for (int kt = 0; kt < 8; ++kt){
    sh8 wh[2], wl[2];
    #pragma unroll
    for (int mi = 0; mi < 2; ++mi){
      int fi = ((kt * 8 + w * 2 + mi) * 64 + l) * 8;
      wh[mi] = *(const sh8*)(W2h + fi);
      wl[mi] = *(const sh8*)(W2l + fi);
    }
    sh8 uh[4], ul[4];
    #pragma unroll
    for (int nt = 0; nt < 4; ++nt){
      int fo = ((kt * 4 + nt) * 64 + l) * 8;
      uh[nt] = *(const sh8*)(Ufh + fo);
      ul[nt] = *(const sh8*)(Ufl + fo);
    }
    #pragma unroll
    for (int mi = 0; mi < 2; ++mi)
      #pragma unroll
      for (int nt = 0; nt < 4; ++nt){
        a2[mi][nt] = __builtin_amdgcn_mfma_f32_16x16x32_bf16(wh[mi], uh[nt], a2[mi][nt], 0, 0, 0);
        a2[mi][nt] = __builtin_amdgcn_mfma_f32_16x16x32_bf16(wh[mi], ul[nt], a2[mi][nt], 0, 0, 0);
        a2[mi][nt] = __builtin_amdgcn_mfma_f32_16x16x32_bf16(wl[mi], uh[nt], a2[mi][nt], 0, 0, 0);
      }
  }
  __syncthreads();

  // ---- bounce X2^T tiles through LDS (swizzled) to get row-major output ----
  float* Xb = (float*)Ufh;          // reuse 32KB as [64 node][128 xcol] f32
  #pragma unroll
  for (int mi = 0; mi < 2; ++mi)
    #pragma unroll
    for (int nt = 0; nt < 4; ++nt){
      int node = nt * 16 + nl;
      int xc = (w * 2 + mi) * 16 + g * 4;
      int idx = node * DD + (xc ^ ((node & 7) << 2));
      *(f32x4*)(Xb + idx) = a2[mi][nt];
    }
  __syncthreads();

  // ---- epilogue: + b2 (+ Xres); write X; LN_next+ReLU -> Z, or doFin dot -> y ----
  {
    int en = tid >> 2, ec = tid & 3;
    f32x4 vr[8];
    float s1e = 0.f, s2e = 0.f;
    #pragma unroll
    for (int i = 0; i < 8; ++i){
      int q = ec + i * 4;           // 16B unit index 0..31
      int c = q * 4;
      int idx = en * DD + ((q ^ (en & 7)) << 2);
      f32x4 v = *(const f32x4*)(Xb + idx);
      v += *(const f32x4*)(b2 + c);
      if (hasRes) v += *(const f32x4*)(Xres + (size_t)(n0 + en) * DD + c);
      vr[i] = v;
      #pragma unroll
      for (int r = 0; r < 4; ++r){ s1e += v[r]; s2e += v[r] * v[r]; }
    }
    s1e += __shfl_xor(s1e, 1); s2e += __shfl_xor(s2e, 1);
    s1e += __shfl_xor(s1e, 2); s2e += __shfl_xor(s2e, 2);
    float mean = s1e * (1.f / DD);
    float var  = s2e * (1.f / DD) - mean * mean;
    float rs   = 1.f / sqrtf(var + 1e-5f);
    float p = 0.f;
    #pragma unroll
    for (int i = 0; i < 8; ++i){
      int q = ec + i * 4;
      int c = q * 4;
      if (writeX) *(f32x4*)(Xout + (size_t)(n0 + en) * DD + c) = vr[i];
      f32x4 gv = *(const f32x4*)(lnG + c);
      f32x4 bv = *(const f32x4*)(lnB + c);
      f32x4 z;
      #pragma unroll
      for (int r = 0; r < 4; ++r)
        z[r] = fmaxf((vr[i][r] - mean) * rs * gv[r] + bv[r], 0.f);
      if (doFin){
        f32x4 lw = *(const f32x4*)(linW + c);
        #pragma unroll
        for (int r = 0; r < 4; ++r) p = fmaf(z[r], lw[r], p);
      } else {
        *(f32x4*)(Zout + (size_t)(n0 + en) * DD + c) = z;
      }
    }
    if (doFin){
      p += __shfl_xor(p, 1); p += __shfl_xor(p, 2);
      if (ec == 0) yv[n0 + en] = p;
    }
  }
}

// ---------------- final subtract: out[i] = y[i] - y[graph base] ----------------
__global__ void k_fin2(const float* __restrict__ y, float* __restrict__ out){
  int i = blockIdx.x * 256 + threadIdx.x;
  out[i] = y[i] - y[i & ~(NPER - 1)];
}

extern "C" void kernel_launch(void* const* d_in, const int* in_sizes, int n_in,
                              void* d_out, int out_size, void* d_ws, size_t ws_size,
                              hipStream_t stream){
  const float* flat_c = (const float*)d_in[0];
  const float* edge_w = (const float*)d_in[1];
  const int*   eidx   = (const int*)  d_in[2];
  const float* nodeW  = (const float*)d_in[3];
  const float* nodeB  = (const float*)d_in[4];
  const float* edgeW  = (const float*)d_in[5];
  const float* edgeB  = (const float*)d_in[6];
  const float* ts     = (const float*)d_in[7];
  const float* W1     = (const float*)d_in[8];
  const float* b1     = (const float*)d_in[9];
  const float* g1     = (const float*)d_in[10];
  const float* be1    = (const float*)d_in[11];
  const float* W2     = (const float*)d_in[12];
  const float* b2     = (const float*)d_in[13];
  const float* lng    = (const float*)d_in[14];
  const float* lnb    = (const float*)d_in[15];
  const float* linW   = (const float*)d_in[16];
  float* out = (float*)d_out;

  char* wsp = (char*)d_ws;
  size_t off = 0;
  auto alloc = [&](size_t bytes) -> void* {
    void* p = wsp + off;
    off += (bytes + 255) & ~(size_t)255;
    return p;
  };
  float*  bufA = (float*) alloc((size_t)NN * DD * 4);   // Z (f32)
  float*  bufB = (float*) alloc((size_t)NN * DD * 4);   // X (f32)
  ushort* Hhi  = (ushort*)alloc((size_t)NN * DD * 2);   // H hi plane
  ushort* Hlo  = (ushort*)alloc((size_t)NN * DD * 2);   // H lo plane
  ushort* W1h  = (ushort*)alloc((size_t)4 * 32768 * 2);
  ushort* W1l  = (ushort*)alloc((size_t)4 * 32768 * 2);
  ushort* W2h  = (ushort*)alloc((size_t)4 * 32768 * 2);
  ushort* W2l  = (ushort*)alloc((size_t)4 * 32768 * 2);
  int*   cnt   = (int*)  alloc((size_t)NN * 4);         // cnt+cur adjacent: one memset
  int*   cur   = (int*)  alloc((size_t)NN * 4);
  int*   rowpt = (int*)  alloc((size_t)(NN + 1) * 4);
  int*   es    = (int*)  alloc((size_t)EE * 4);
  float* ewS   = (float*)alloc((size_t)EE * 4);
  float* y     = (float*)alloc((size_t)NN * 4);
  if (off > ws_size) return;

  const int* srcI = eidx;
  const int* dstI = eidx + EE;

  (void)hipMemsetAsync(cnt, 0, (size_t)2 * NN * 4, stream);   // covers cnt and cur
  k_count_pack<<<2176, 256, 0, stream>>>(dstI, cnt, W1, W2, W1h, W1l, W2h, W2l);
  k_scan   <<<1, 1024, 0, stream>>>(cnt, rowpt);
  k_scatter<<<EE / 256, 256, 0, stream>>>(srcI, dstI, edge_w, rowpt, cur, es, ewS);

  for (int l = 0; l < 4; ++l){
    if (l == 0)
      k_edge<0><<<NN / 2, 256, 0, stream>>>(nullptr, flat_c, nodeW, nodeB,
                                            rowpt, es, ewS, edgeW, edgeB, ts, l, Hhi, Hlo);
    else
      k_edge<1><<<NN / 2, 256, 0, stream>>>(bufA, nullptr, nullptr, nullptr,
                                            rowpt, es, ewS, edgeW, edgeB, ts, l, Hhi, Hlo);
    int nx = (l + 1) & 3;           // next pre-LN params; l=3 -> ln[0] (final LN)
    k_mlp <<<NN / 64, 256, 0, stream>>>(Hhi, Hlo,
                                        W1h + (size_t)l * 32768, W1l + (size_t)l * 32768,
                                        b1 + l * D2, g1 + l * D2, be1 + l * D2,
                                        W2h + (size_t)l * 32768, W2l + (size_t)l * 32768,
                                        b2 + l * DD, bufB, bufB,
                                        lng + nx * DD, lnb + nx * DD, bufA,
                                        linW, y,
                                        l > 0 ? 1 : 0, l < 3 ? 1 : 0, l == 3 ? 1 : 0);
  }
  k_fin2<<<NN / 256, 256, 0, stream>>>(y, out);
}

// Round 14
// 302.264 us; speedup vs baseline: 1.1298x; 1.1298x over previous
//
#include <hip/hip_runtime.h>
#include <hip/hip_bf16.h>
#include <stdint.h>

#define NN   32768
#define EE   524288
#define DD   128
#define D2   256
#define NPER 2048

using f32x4 = __attribute__((ext_vector_type(4))) float;
using sh8   = __attribute__((ext_vector_type(8))) short;
using sh4   = __attribute__((ext_vector_type(4))) short;

__device__ inline uint32_t rtn_hi_bits(float x){
  uint32_t u = __float_as_uint(x);
  return (u + 0x7FFFu + ((u >> 16) & 1u)) & 0xFFFF0000u;
}

// XCD-contiguous node mapping (8 XCDs, round-robin block dispatch)
__device__ inline int swz_node(int blk, int wave){
  int s = (blk & 7) * 1024 + (blk >> 3);
  return s * 4 + wave;
}

// ---------------- CSR build ----------------
__global__ __launch_bounds__(1024)
void k_scan(const int* __restrict__ cnt, int* __restrict__ rowptr){
  __shared__ int ps[1024];
  int t = threadIdx.x;
  int loc[32];
  int base = t * 32;
  int s = 0;
  #pragma unroll
  for (int j = 0; j < 32; ++j){ loc[j] = cnt[base + j]; s += loc[j]; }
  ps[t] = s; __syncthreads();
  for (int off = 1; off < 1024; off <<= 1){
    int v = (t >= off) ? ps[t - off] : 0;
    __syncthreads();
    ps[t] += v;
    __syncthreads();
  }
  int run = ps[t] - s;
  #pragma unroll
  for (int j = 0; j < 32; ++j){ rowptr[base + j] = run; run += loc[j]; }
  if (t == 1023) rowptr[NN] = run;
}

__global__ void k_scatter(const int* __restrict__ src, const int* __restrict__ dst,
                          const float* __restrict__ w, const int* __restrict__ rowptr,
                          int* __restrict__ cur, int* __restrict__ es, float* __restrict__ ew){
  int e = blockIdx.x * 256 + threadIdx.x;
  if (e < EE){
    int d = dst[e];
    int pos = rowptr[d] + atomicAdd(&cur[d], 1);
    es[pos] = src[e];
    ew[pos] = w[e];
  }
}

// ---------------- fused: degree count (blocks 0..2047) + weight prepack (2048..2175) ----------------
// A-frag (16x16x32): lane l holds A[m = l&15][k = (l>>4)*4 + (j&3) + 16*(j>>2)], j=0..7
__global__ __launch_bounds__(256)
void k_count_pack(const int* __restrict__ dst, int* __restrict__ cnt,
                  const float* __restrict__ W1, const float* __restrict__ W2,
                  ushort* __restrict__ W1h, ushort* __restrict__ W1l,
                  ushort* __restrict__ W2h, ushort* __restrict__ W2l){
  int b = blockIdx.x;
  if (b < 2048){
    int e = b * 256 + threadIdx.x;
    atomicAdd(&cnt[dst[e]], 1);
  } else if (b < 2112){
    int t = (b - 2048) * 256 + threadIdx.x;   // t = (((layer*4+kt)*16+mt)*64+lane)
    int lane = t & 63, mt = (t >> 6) & 15, kt = (t >> 10) & 3, layer = t >> 12;
    int nl = lane & 15, g = lane >> 4;
    int ucol = mt * 16 + nl;
    const float* Wp = W1 + layer * (DD * D2);
    sh8 hh, ll;
    #pragma unroll
    for (int j = 0; j < 8; ++j){
      int k = kt * 32 + g * 4 + (j & 3) + 16 * (j >> 2);
      float v = Wp[k * D2 + ucol];             // W1^T[ucol][k]
      uint32_t hb = rtn_hi_bits(v);
      hh[j] = (short)(hb >> 16);
      ll[j] = (short)(__float_as_uint(v - __uint_as_float(hb)) >> 16);
    }
    *(sh8*)(W1h + t * 8) = hh;
    *(sh8*)(W1l + t * 8) = ll;
  } else {
    int t = (b - 2112) * 256 + threadIdx.x;   // t = (((layer*8+kt)*8+mt)*64+lane)
    int lane = t & 63, mt = (t >> 6) & 7, kt = (t >> 9) & 7, layer = t >> 12;
    int nl = lane & 15, g = lane >> 4;
    int xcol = mt * 16 + nl;
    const float* Wp = W2 + layer * (D2 * DD);
    sh8 hh, ll;
    #pragma unroll
    for (int j = 0; j < 8; ++j){
      int k = kt * 32 + g * 4 + (j & 3) + 16 * (j >> 2); // k = ucol
      float v = Wp[k * DD + xcol];             // W2^T[xcol][ucol]
      uint32_t hb = rtn_hi_bits(v);
      hh[j] = (short)(hb >> 16);
      ll[j] = (short)(__float_as_uint(v - __uint_as_float(hb)) >> 16);
    }
    *(sh8*)(W2h + t * 8) = hh;
    *(sh8*)(W2l + t * 8) = ll;
  }
}

// ---------------- edge aggregation -> H emitted as bf16 hi/lo planes (round-6 exact) ----------------
template<int MODE>
__global__ __launch_bounds__(256)
void k_edge(const float* __restrict__ Zf, const float* __restrict__ cvec,
            const float* __restrict__ nW, const float* __restrict__ nb,
            const int* __restrict__ rowptr,
            const int* __restrict__ es, const float* __restrict__ ew,
            const float* __restrict__ eW, const float* __restrict__ eB,
            const float* __restrict__ ts, int layer,
            ushort* __restrict__ Hh, ushort* __restrict__ Hl){
  int n  = swz_node(blockIdx.x, threadIdx.x >> 6);
  int ld = threadIdx.x & 63;
  int d0 = ld * 2;
  float t  = ts[layer];
  float wx = eW[d0], wy = eW[d0 + 1];
  float bx = eB[d0], by = eB[d0 + 1];
  float nwx = 0.f, nwy = 0.f, nbx = 0.f, nby = 0.f;
  if (MODE == 0){ nwx = nW[d0]; nwy = nW[d0 + 1]; nbx = nb[d0]; nby = nb[d0 + 1]; }
  int r0 = __builtin_amdgcn_readfirstlane(rowptr[n]);
  int r1 = __builtin_amdgcn_readfirstlane(rowptr[n + 1]);

  float s0a = 0.f, s1a = 0.f, a0a = 0.f, a1a = 0.f;

  auto body = [&](float zx, float zy, float wj){
    float m0 = fmaxf(zx + fmaf(wj, wx, bx), 0.f) + 1e-7f;
    float m1 = fmaxf(zy + fmaf(wj, wy, by), 0.f) + 1e-7f;
    float p0 = __expf(fminf(m0 * t, 60.f));
    float p1 = __expf(fminf(m1 * t, 60.f));
    s0a += p0; a0a = fmaf(p0, m0, a0a);
    s1a += p1; a1a = fmaf(p1, m1, a1a);
  };

  int j = r0;
  for (; j + 4 <= r1; j += 4){
    int   sA = es[j],     sB = es[j + 1], sC = es[j + 2], sD = es[j + 3];
    float wA = ew[j],     wB = ew[j + 1], wC = ew[j + 2], wD = ew[j + 3];
    float zAx, zAy, zBx, zBy, zCx, zCy, zDx, zDy;
    if (MODE == 0){
      float cA = cvec[sA], cB = cvec[sB], cC = cvec[sC], cD = cvec[sD];
      zAx = fmaf(cA, nwx, nbx); zAy = fmaf(cA, nwy, nby);
      zBx = fmaf(cB, nwx, nbx); zBy = fmaf(cB, nwy, nby);
      zCx = fmaf(cC, nwx, nbx); zCy = fmaf(cC, nwy, nby);
      zDx = fmaf(cD, nwx, nbx); zDy = fmaf(cD, nwy, nby);
    } else {
      float2 zA = *(const float2*)(Zf + (size_t)sA * DD + d0);
      float2 zB = *(const float2*)(Zf + (size_t)sB * DD + d0);
      float2 zC = *(const float2*)(Zf + (size_t)sC * DD + d0);
      float2 zD = *(const float2*)(Zf + (size_t)sD * DD + d0);
      zAx = zA.x; zAy = zA.y; zBx = zB.x; zBy = zB.y;
      zCx = zC.x; zCy = zC.y; zDx = zD.x; zDy = zD.y;
    }
    body(zAx, zAy, wA); body(zBx, zBy, wB);
    body(zCx, zCy, wC); body(zDx, zDy, wD);
  }
  for (; j < r1; ++j){
    int s = es[j]; float w = ew[j];
    float zx, zy;
    if (MODE == 0){
      float cs = cvec[s];
      zx = fmaf(cs, nwx, nbx); zy = fmaf(cs, nwy, nby);
    } else {
      float2 z = *(const float2*)(Zf + (size_t)s * DD + d0);
      zx = z.x; zy = z.y;
    }
    body(zx, zy, w);
  }

  float znx, zny;
  if (MODE == 0){
    float cn = cvec[n];
    znx = fmaf(cn, nwx, nbx); zny = fmaf(cn, nwy, nby);
  } else {
    float2 zn2 = *(const float2*)(Zf + (size_t)n * DD + d0);
    znx = zn2.x; zny = zn2.y;
  }
  float hx = fmaf(a0a, __builtin_amdgcn_rcpf(s0a + 1e-16f), znx);
  float hy = fmaf(a1a, __builtin_amdgcn_rcpf(s1a + 1e-16f), zny);
  uint32_t hbx = rtn_hi_bits(hx), hby = rtn_hi_bits(hy);
  uint32_t hw = (hbx >> 16) | (hby & 0xFFFF0000u);
  float lx = hx - __uint_as_float(hbx), ly = hy - __uint_as_float(hby);
  uint32_t lw = (__float_as_uint(lx) >> 16) | (__float_as_uint(ly) & 0xFFFF0000u);
  ((uint32_t*)(Hh + (size_t)n * DD))[ld] = hw;
  ((uint32_t*)(Hl + (size_t)n * DD))[ld] = lw;
}

// ---------------- fused MFMA MLP (+ next-layer pre-LN, or final projection) ----------------
__global__ __launch_bounds__(256, 2)
void k_mlp(const ushort* __restrict__ Hhi, const ushort* __restrict__ Hlo,
           const ushort* __restrict__ W1h, const ushort* __restrict__ W1l,
           const float* __restrict__ b1, const float* __restrict__ g1,
           const float* __restrict__ be1,
           const ushort* __restrict__ W2h, const ushort* __restrict__ W2l,
           const float* __restrict__ b2, const float* __restrict__ Xres,
           float* __restrict__ Xout,
           const float* __restrict__ lnG, const float* __restrict__ lnB,
           float* __restrict__ Zout,
           const float* __restrict__ linW, float* __restrict__ yv,
           int hasRes, int writeX, int doFin)
{
  __shared__ ushort Ufh[16384];     // 32KB: U' hi frags [8kt][4nt][64lane][8]
  __shared__ ushort Ufl[16384];     // 32KB: U' lo frags
  __shared__ float2 Pln[256];       // [64 node][4 wave] LN partials

  const int tid = threadIdx.x;
  const int w = tid >> 6, l = tid & 63, nl = l & 15, g = l >> 4;
  const int bs = (blockIdx.x & 7) * 64 + (blockIdx.x >> 3);
  const int n0 = bs * 64;

  f32x4 acc[4][4];                  // [mi(ucol tile)][nt(node tile)]
  #pragma unroll
  for (int mi = 0; mi < 4; ++mi)
    #pragma unroll
    for (int nt = 0; nt < 4; ++nt) acc[mi][nt] = (f32x4)0.f;

  const int hbase = (n0 + nl) * DD + g * 4;

  // ---- GEMM1: U^T = W1^T · H^T, K = 128 (4 ksteps) ----
  #pragma unroll
  for (int kt = 0; kt < 4; ++kt){
    sh8 ah[4], al[4];
    #pragma unroll
    for (int mi = 0; mi < 4; ++mi){
      int fi = ((kt * 16 + w * 4 + mi) * 64 + l) * 8;
      ah[mi] = *(const sh8*)(W1h + fi);
      al[mi] = *(const sh8*)(W1l + fi);
    }
    sh8 bh[4], bl[4];
    #pragma unroll
    for (int nt = 0; nt < 4; ++nt){
      int hi_ = hbase + nt * 16 * DD + kt * 32;
      sh8 vh, vl;
      ((sh4*)&vh)[0] = *(const sh4*)(Hhi + hi_);
      ((sh4*)&vh)[1] = *(const sh4*)(Hhi + hi_ + 16);
      ((sh4*)&vl)[0] = *(const sh4*)(Hlo + hi_);
      ((sh4*)&vl)[1] = *(const sh4*)(Hlo + hi_ + 16);
      bh[nt] = vh; bl[nt] = vl;
    }
    #pragma unroll
    for (int mi = 0; mi < 4; ++mi)
      #pragma unroll
      for (int nt = 0; nt < 4; ++nt){
        acc[mi][nt] = __builtin_amdgcn_mfma_f32_16x16x32_bf16(ah[mi], bh[nt], acc[mi][nt], 0, 0, 0);
        acc[mi][nt] = __builtin_amdgcn_mfma_f32_16x16x32_bf16(ah[mi], bl[nt], acc[mi][nt], 0, 0, 0);
        acc[mi][nt] = __builtin_amdgcn_mfma_f32_16x16x32_bf16(al[mi], bh[nt], acc[mi][nt], 0, 0, 0);
      }
  }

  // ---- + b1, LN(256) stats (partial per wave, combine via LDS) ----
  #pragma unroll
  for (int mi = 0; mi < 4; ++mi){
    f32x4 bv = *(const f32x4*)(b1 + w * 64 + mi * 16 + g * 4);
    #pragma unroll
    for (int nt = 0; nt < 4; ++nt) acc[mi][nt] += bv;
  }
  float s1[4], s2[4];
  #pragma unroll
  for (int nt = 0; nt < 4; ++nt){
    float a = 0.f, b = 0.f;
    #pragma unroll
    for (int mi = 0; mi < 4; ++mi)
      #pragma unroll
      for (int r = 0; r < 4; ++r){ float v = acc[mi][nt][r]; a += v; b += v * v; }
    a += __shfl_xor(a, 16); b += __shfl_xor(b, 16);
    a += __shfl_xor(a, 32); b += __shfl_xor(b, 32);
    s1[nt] = a; s2[nt] = b;
  }
  {
    float p1 = (g == 0) ? s1[0] : (g == 1) ? s1[1] : (g == 2) ? s1[2] : s1[3];
    float p2 = (g == 0) ? s2[0] : (g == 1) ? s2[1] : (g == 2) ? s2[2] : s2[3];
    Pln[(g * 16 + nl) * 4 + w] = make_float2(p1, p2);
  }
  __syncthreads();

  // ---- LN apply + ReLU + split to bf16 hi/lo frags in LDS ----
  {
    f32x4 gv[4], ev[4];
    #pragma unroll
    for (int mi = 0; mi < 4; ++mi){
      gv[mi] = *(const f32x4*)(g1  + w * 64 + mi * 16 + g * 4);
      ev[mi] = *(const f32x4*)(be1 + w * 64 + mi * 16 + g * 4);
    }
    #pragma unroll
    for (int nt = 0; nt < 4; ++nt){
      int node = nt * 16 + nl;
      float t1 = 0.f, t2 = 0.f;
      #pragma unroll
      for (int wi = 0; wi < 4; ++wi){
        float2 pp = Pln[node * 4 + wi];
        t1 += pp.x; t2 += pp.y;
      }
      float mean = t1 * (1.f / D2);
      float var  = t2 * (1.f / D2) - mean * mean;
      float rstd = 1.f / sqrtf(var + 1e-5f);
      #pragma unroll
      for (int p = 0; p < 2; ++p){
        sh8 uh, ul;
        #pragma unroll
        for (int j = 0; j < 8; ++j){
          int mi = 2 * p + (j >> 2), r = j & 3;
          float v = (acc[mi][nt][r] - mean) * rstd * gv[mi][r] + ev[mi][r];
          v = fmaxf(v, 0.f);
          uint32_t hb = rtn_hi_bits(v);
          uh[j] = (short)(hb >> 16);
          ul[j] = (short)(__float_as_uint(v - __uint_as_float(hb)) >> 16);
        }
        int fo = (((2 * w + p) * 4 + nt) * 64 + l) * 8;
        *(sh8*)(Ufh + fo) = uh;
        *(sh8*)(Ufl + fo) = ul;
      }
    }
  }
  __syncthreads();

  // ---- GEMM2: X2^T = W2^T · U'^T, K = 256 (8 ksteps) ----
  f32x4 a2[2][4];
  #pragma unroll
  for (int mi = 0; mi < 2; ++mi)
    #pragma unroll
    for (int nt = 0; nt < 4; ++nt) a2[mi][nt] = (f32x4)0.f;
  #pragma unroll
  for (int kt = 0; kt < 8; ++kt){
    sh8 wh[2], wl[2];
    #pragma unroll
    for (int mi = 0; mi < 2; ++mi){
      int fi = ((kt * 8 + w * 2 + mi) * 64 + l) * 8;
      wh[mi] = *(const sh8*)(W2h + fi);
      wl[mi] = *(const sh8*)(W2l + fi);
    }
    sh8 uh[4], ul[4];
    #pragma unroll
    for (int nt = 0; nt < 4; ++nt){
      int fo = ((kt * 4 + nt) * 64 + l) * 8;
      uh[nt] = *(const sh8*)(Ufh + fo);
      ul[nt] = *(const sh8*)(Ufl + fo);
    }
    #pragma unroll
    for (int mi = 0; mi < 2; ++mi)
      #pragma unroll
      for (int nt = 0; nt < 4; ++nt){
        a2[mi][nt] = __builtin_amdgcn_mfma_f32_16x16x32_bf16(wh[mi], uh[nt], a2[mi][nt], 0, 0, 0);
        a2[mi][nt] = __builtin_amdgcn_mfma_f32_16x16x32_bf16(wh[mi], ul[nt], a2[mi][nt], 0, 0, 0);
        a2[mi][nt] = __builtin_amdgcn_mfma_f32_16x16x32_bf16(wl[mi], uh[nt], a2[mi][nt], 0, 0, 0);
      }
  }
  __syncthreads();

  // ---- bounce X2^T tiles through LDS (swizzled) to get row-major output ----
  float* Xb = (float*)Ufh;          // reuse 32KB as [64 node][128 xcol] f32
  #pragma unroll
  for (int mi = 0; mi < 2; ++mi)
    #pragma unroll
    for (int nt = 0; nt < 4; ++nt){
      int node = nt * 16 + nl;
      int xc = (w * 2 + mi) * 16 + g * 4;
      int idx = node * DD + (xc ^ ((node & 7) << 2));
      *(f32x4*)(Xb + idx) = a2[mi][nt];
    }
  __syncthreads();

  // ---- epilogue: + b2 (+ Xres); write X; LN_next+ReLU -> Z, or doFin dot -> y ----
  {
    int en = tid >> 2, ec = tid & 3;
    f32x4 vr[8];
    float s1e = 0.f, s2e = 0.f;
    #pragma unroll
    for (int i = 0; i < 8; ++i){
      int q = ec + i * 4;           // 16B unit index 0..31
      int c = q * 4;
      int idx = en * DD + ((q ^ (en & 7)) << 2);
      f32x4 v = *(const f32x4*)(Xb + idx);
      v += *(const f32x4*)(b2 + c);
      if (hasRes) v += *(const f32x4*)(Xres + (size_t)(n0 + en) * DD + c);
      vr[i] = v;
      #pragma unroll
      for (int r = 0; r < 4; ++r){ s1e += v[r]; s2e += v[r] * v[r]; }
    }
    s1e += __shfl_xor(s1e, 1); s2e += __shfl_xor(s2e, 1);
    s1e += __shfl_xor(s1e, 2); s2e += __shfl_xor(s2e, 2);
    float mean = s1e * (1.f / DD);
    float var  = s2e * (1.f / DD) - mean * mean;
    float rs   = 1.f / sqrtf(var + 1e-5f);
    float p = 0.f;
    #pragma unroll
    for (int i = 0; i < 8; ++i){
      int q = ec + i * 4;
      int c = q * 4;
      if (writeX) *(f32x4*)(Xout + (size_t)(n0 + en) * DD + c) = vr[i];
      f32x4 gv = *(const f32x4*)(lnG + c);
      f32x4 bv = *(const f32x4*)(lnB + c);
      f32x4 z;
      #pragma unroll
      for (int r = 0; r < 4; ++r)
        z[r] = fmaxf((vr[i][r] - mean) * rs * gv[r] + bv[r], 0.f);
      if (doFin){
        f32x4 lw = *(const f32x4*)(linW + c);
        #pragma unroll
        for (int r = 0; r < 4; ++r) p = fmaf(z[r], lw[r], p);
      } else {
        *(f32x4*)(Zout + (size_t)(n0 + en) * DD + c) = z;
      }
    }
    if (doFin){
      p += __shfl_xor(p, 1); p += __shfl_xor(p, 2);
      if (ec == 0) yv[n0 + en] = p;
    }
  }
}

// ---------------- final subtract: out[i] = y[i] - y[graph base] ----------------
__global__ void k_fin2(const float* __restrict__ y, float* __restrict__ out){
  int i = blockIdx.x * 256 + threadIdx.x;
  out[i] = y[i] - y[i & ~(NPER - 1)];
}

extern "C" void kernel_launch(void* const* d_in, const int* in_sizes, int n_in,
                              void* d_out, int out_size, void* d_ws, size_t ws_size,
                              hipStream_t stream){
  const float* flat_c = (const float*)d_in[0];
  const float* edge_w = (const float*)d_in[1];
  const int*   eidx   = (const int*)  d_in[2];
  const float* nodeW  = (const float*)d_in[3];
  const float* nodeB  = (const float*)d_in[4];
  const float* edgeW  = (const float*)d_in[5];
  const float* edgeB  = (const float*)d_in[6];
  const float* ts     = (const float*)d_in[7];
  const float* W1     = (const float*)d_in[8];
  const float* b1     = (const float*)d_in[9];
  const float* g1     = (const float*)d_in[10];
  const float* be1    = (const float*)d_in[11];
  const float* W2     = (const float*)d_in[12];
  const float* b2     = (const float*)d_in[13];
  const float* lng    = (const float*)d_in[14];
  const float* lnb    = (const float*)d_in[15];
  const float* linW   = (const float*)d_in[16];
  float* out = (float*)d_out;

  char* wsp = (char*)d_ws;
  size_t off = 0;
  auto alloc = [&](size_t bytes) -> void* {
    void* p = wsp + off;
    off += (bytes + 255) & ~(size_t)255;
    return p;
  };
  float*  bufA = (float*) alloc((size_t)NN * DD * 4);   // Z (f32)
  float*  bufB = (float*) alloc((size_t)NN * DD * 4);   // X (f32)
  ushort* Hhi  = (ushort*)alloc((size_t)NN * DD * 2);   // H hi plane
  ushort* Hlo  = (ushort*)alloc((size_t)NN * DD * 2);   // H lo plane
  ushort* W1h  = (ushort*)alloc((size_t)4 * 32768 * 2);
  ushort* W1l  = (ushort*)alloc((size_t)4 * 32768 * 2);
  ushort* W2h  = (ushort*)alloc((size_t)4 * 32768 * 2);
  ushort* W2l  = (ushort*)alloc((size_t)4 * 32768 * 2);
  int*   cnt   = (int*)  alloc((size_t)NN * 4);         // cnt+cur adjacent: one memset
  int*   cur   = (int*)  alloc((size_t)NN * 4);
  int*   rowpt = (int*)  alloc((size_t)(NN + 1) * 4);
  int*   es    = (int*)  alloc((size_t)EE * 4);
  float* ewS   = (float*)alloc((size_t)EE * 4);
  float* y     = (float*)alloc((size_t)NN * 4);
  if (off > ws_size) return;

  const int* srcI = eidx;
  const int* dstI = eidx + EE;

  (void)hipMemsetAsync(cnt, 0, (size_t)2 * NN * 4, stream);   // covers cnt and cur
  k_count_pack<<<2176, 256, 0, stream>>>(dstI, cnt, W1, W2, W1h, W1l, W2h, W2l);
  k_scan   <<<1, 1024, 0, stream>>>(cnt, rowpt);
  k_scatter<<<EE / 256, 256, 0, stream>>>(srcI, dstI, edge_w, rowpt, cur, es, ewS);

  for (int l = 0; l < 4; ++l){
    if (l == 0)
      k_edge<0><<<NN / 4, 256, 0, stream>>>(nullptr, flat_c, nodeW, nodeB,
                                            rowpt, es, ewS, edgeW, edgeB, ts, l, Hhi, Hlo);
    else
      k_edge<1><<<NN / 4, 256, 0, stream>>>(bufA, nullptr, nullptr, nullptr,
                                            rowpt, es, ewS, edgeW, edgeB, ts, l, Hhi, Hlo);
    int nx = (l + 1) & 3;           // next pre-LN params; l=3 -> ln[0] (final LN)
    k_mlp <<<NN / 64, 256, 0, stream>>>(Hhi, Hlo,
                                        W1h + (size_t)l * 32768, W1l + (size_t)l * 32768,
                                        b1 + l * D2, g1 + l * D2, be1 + l * D2,
                                        W2h + (size_t)l * 32768, W2l + (size_t)l * 32768,
                                        b2 + l * DD, bufB, bufB,
                                        lng + nx * DD, lnb + nx * DD, bufA,
                                        linW, y,
                                        l > 0 ? 1 : 0, l < 3 ? 1 : 0, l == 3 ? 1 : 0);
  }
  k_fin2<<<NN / 256, 256, 0, stream>>>(y, out);
}